// Round 2
// baseline (1219.877 us; speedup 1.0000x reference)
//
#include <hip/hip_runtime.h>

// ---------- problem dims ----------
constexpr int BN = 32;      // batch
constexpr int DM = 512;     // d_model = d_inner
constexpr int SD = 64;      // state dim S
constexpr int LL = 4096;    // L = 64*64
constexpr int C3 = 192;     // 3*S

// 16 FMAs of the 4x4 outer product (used by the small K5 GEMMs)
#define OUTER16(acc, a4, b4)                                               \
    acc[0][0] += a4.x * b4.x; acc[0][1] += a4.x * b4.y;                    \
    acc[0][2] += a4.x * b4.z; acc[0][3] += a4.x * b4.w;                    \
    acc[1][0] += a4.y * b4.x; acc[1][1] += a4.y * b4.y;                    \
    acc[1][2] += a4.y * b4.z; acc[1][3] += a4.y * b4.w;                    \
    acc[2][0] += a4.z * b4.x; acc[2][1] += a4.z * b4.y;                    \
    acc[2][2] += a4.z * b4.z; acc[2][3] += a4.z * b4.w;                    \
    acc[3][0] += a4.w * b4.x; acc[3][1] += a4.w * b4.y;                    \
    acc[3][2] += a4.w * b4.z; acc[3][3] += a4.w * b4.w;

// 64 FMAs of the 8x8 outer product from two float4 pairs
#define OUTER64(acc, a0, a1, b0, b1)                                       \
    {                                                                      \
        float af[8] = {a0.x, a0.y, a0.z, a0.w, a1.x, a1.y, a1.z, a1.w};    \
        float bf[8] = {b0.x, b0.y, b0.z, b0.w, b1.x, b1.y, b1.z, b1.w};    \
        _Pragma("unroll")                                                  \
        for (int i_ = 0; i_ < 8; ++i_)                                     \
            _Pragma("unroll")                                              \
            for (int j_ = 0; j_ < 8; ++j_) acc[i_][j_] += af[i_] * bf[j_]; \
    }

// ---------- K1: bcdt[b,o,l] = sum_c w[o,c]*x[b,c,l] + bias[o]  (M=192,N=4096,K=512) ----------
// v3: 64x256 tile, acc 8x8/thread (broadcast-heavy LDS reads), XOR pair-swizzled x tile.
__global__ __launch_bounds__(256) void k1_bcdt(const float* __restrict__ x,
                                               const float* __restrict__ w,
                                               const float* __restrict__ bias,
                                               float* __restrict__ out) {
    int o0 = blockIdx.x * 64;       // 3 o-tiles
    int l0 = blockIdx.y * 256;      // 16 l-tiles
    int b  = blockIdx.z;
    __shared__ float  wl[16][68];   // [k][o]
    __shared__ float4 xl4[16][66];  // [k][l/4], swizzled f4 positions
    int t = threadIdx.x;
    int tx = t & 31, ty = t >> 5;   // tx: l-group (8 l), ty: o-group (8 o)
    float acc[8][8] = {};
    const float* xb = x + (size_t)b * DM * LL;

    // staging: w — thread reads f4 of row (o0+wo) at k-chunk wk
    int wo = t & 63, wk = t >> 6;
    // staging: x — thread reads 4 f4 (row kr, f4-blocks cb = cbase+16j)
    int kr = t >> 4, cbase = t & 15;
    int wpos[4];
#pragma unroll
    for (int j = 0; j < 4; ++j) {
        int cb = cbase + 16 * j, pb = cb >> 1;
        wpos[j] = ((pb ^ ((pb >> 2) & 3)) << 1) | (cb & 1);
    }
    int rp = (tx ^ ((tx >> 2) & 3)) * 2;   // swizzled f4 index of this thread's b-frag

    float4 wv = *(const float4*)&w[(size_t)(o0 + wo) * DM + wk * 4];
    float4 xv[4];
#pragma unroll
    for (int j = 0; j < 4; ++j)
        xv[j] = *(const float4*)&xb[(size_t)kr * LL + l0 + (cbase + 16 * j) * 4];

    for (int k0 = 0; k0 < DM; k0 += 16) {
        wl[wk * 4 + 0][wo] = wv.x; wl[wk * 4 + 1][wo] = wv.y;
        wl[wk * 4 + 2][wo] = wv.z; wl[wk * 4 + 3][wo] = wv.w;
#pragma unroll
        for (int j = 0; j < 4; ++j) xl4[kr][wpos[j]] = xv[j];
        __syncthreads();
        if (k0 + 16 < DM) {
            wv = *(const float4*)&w[(size_t)(o0 + wo) * DM + k0 + 16 + wk * 4];
#pragma unroll
            for (int j = 0; j < 4; ++j)
                xv[j] = *(const float4*)&xb[(size_t)(k0 + 16 + kr) * LL + l0 + (cbase + 16 * j) * 4];
        }
#pragma unroll
        for (int kk = 0; kk < 16; ++kk) {
            float4 a0 = *(const float4*)&wl[kk][ty * 8];
            float4 a1 = *(const float4*)&wl[kk][ty * 8 + 4];
            float4 b0 = xl4[kk][rp];
            float4 b1 = xl4[kk][rp + 1];
            OUTER64(acc, a0, a1, b0, b1)
        }
        __syncthreads();
    }
#pragma unroll
    for (int i = 0; i < 8; ++i) {
        int o = o0 + ty * 8 + i;
        float bo = bias[o];
        float* op = &out[((size_t)b * C3 + o) * LL + l0 + tx * 8];
        *(float4*)&op[0] = make_float4(acc[i][0] + bo, acc[i][1] + bo, acc[i][2] + bo, acc[i][3] + bo);
        *(float4*)&op[4] = make_float4(acc[i][4] + bo, acc[i][5] + bo, acc[i][6] + bo, acc[i][7] + bo);
    }
}

// ---------- K2': fused depthwise 3x3 conv (Bm,Cm,dt) + softmax + AB, one block per (b,s) ----------
__device__ __forceinline__ void load_plane(const float* __restrict__ plane, float* p, int t) {
    const float4* p4 = (const float4*)plane;
    for (int i = t; i < 1024; i += 256) {
        float4 v = p4[i];
        int yy = i >> 4, xx = (i & 15) << 2;
        float* dst = &p[(yy + 1) * 66 + xx + 1];
        dst[0] = v.x; dst[1] = v.y; dst[2] = v.z; dst[3] = v.w;
    }
}

__device__ __forceinline__ void conv_plane(const float* p, const float* wv, float bias,
                                           int t, float4* out4) {
#pragma unroll
    for (int g = 0; g < 4; ++g) {
        int fi = g * 256 + t;
        int yy = fi >> 4, xx = (fi & 15) << 2;
        float r0[6], r1[6], r2[6];
#pragma unroll
        for (int j = 0; j < 6; ++j) {
            r0[j] = p[(yy + 0) * 66 + xx + j];
            r1[j] = p[(yy + 1) * 66 + xx + j];
            r2[j] = p[(yy + 2) * 66 + xx + j];
        }
        float* op = (float*)&out4[g];
#pragma unroll
        for (int j = 0; j < 4; ++j)
            op[j] = bias + wv[0] * r0[j] + wv[1] * r0[j + 1] + wv[2] * r0[j + 2]
                         + wv[3] * r1[j] + wv[4] * r1[j + 1] + wv[5] * r1[j + 2]
                         + wv[6] * r2[j] + wv[7] * r2[j + 1] + wv[8] * r2[j + 2];
    }
}

__global__ __launch_bounds__(256) void k2_fused(float* __restrict__ buf,
                                                const float* __restrict__ wdw,
                                                const float* __restrict__ bdw,
                                                const float* __restrict__ Ap,
                                                float* __restrict__ cmws) {
    int s = blockIdx.x, b = blockIdx.y;
    __shared__ float p[66 * 66];
    __shared__ float redm[4], reds[4];
    int t = threadIdx.x;
    // zero halo border once (interior overwritten by each load_plane)
    for (int i = t; i < 66; i += 256) { p[i] = 0.f; p[65 * 66 + i] = 0.f; }
    for (int i = t; i < 64; i += 256) { p[(i + 1) * 66] = 0.f; p[(i + 1) * 66 + 65] = 0.f; }

    const float* base = buf + (size_t)b * C3 * LL;
    float wvB[9], wvC[9], wvD[9];
#pragma unroll
    for (int k = 0; k < 9; ++k) {
        wvB[k] = wdw[(size_t)s * 9 + k];
        wvC[k] = wdw[(size_t)(64 + s) * 9 + k];
        wvD[k] = wdw[(size_t)(128 + s) * 9 + k];
    }
    float4 bm4[4], cm4[4], dt4[4];

    load_plane(base + (size_t)s * LL, p, t);            // Bm raw
    __syncthreads();
    conv_plane(p, wvB, bdw[s], t, bm4);
    __syncthreads();
    load_plane(base + (size_t)(64 + s) * LL, p, t);     // Cm raw
    __syncthreads();
    conv_plane(p, wvC, bdw[64 + s], t, cm4);
    __syncthreads();
    {   // write Cm
        float4* cmp4 = (float4*)(cmws + ((size_t)b * SD + s) * LL);
#pragma unroll
        for (int g = 0; g < 4; ++g) cmp4[g * 256 + t] = cm4[g];
    }
    load_plane(base + (size_t)(128 + s) * LL, p, t);    // dt raw
    __syncthreads();
    conv_plane(p, wvD, bdw[128 + s], t, dt4);

    // softmax over the full 4096-plane (each thread holds 16 values)
    float Av = Ap[s];
    float mx = -1e30f;
#pragma unroll
    for (int g = 0; g < 4; ++g) {
        float* v = (float*)&dt4[g];
#pragma unroll
        for (int j = 0; j < 4; ++j) { v[j] += Av; mx = fmaxf(mx, v[j]); }
    }
#pragma unroll
    for (int off = 32; off >= 1; off >>= 1) mx = fmaxf(mx, __shfl_xor(mx, off, 64));
    int wid = t >> 6, lane = t & 63;
    if (lane == 0) redm[wid] = mx;
    __syncthreads();
    mx = fmaxf(fmaxf(redm[0], redm[1]), fmaxf(redm[2], redm[3]));
    float sum = 0.f;
#pragma unroll
    for (int g = 0; g < 4; ++g) {
        float* v = (float*)&dt4[g];
#pragma unroll
        for (int j = 0; j < 4; ++j) { v[j] = expf(v[j] - mx); sum += v[j]; }
    }
#pragma unroll
    for (int off = 32; off >= 1; off >>= 1) sum += __shfl_xor(sum, off, 64);
    if (lane == 0) reds[wid] = sum;
    __syncthreads();
    sum = reds[0] + reds[1] + reds[2] + reds[3];
    float inv = 1.f / sum;
    // AB = softmax * Bm, written over the Bm channel (read fully above; block-exclusive)
    float4* abp4 = (float4*)(buf + ((size_t)b * C3 + s) * LL);
#pragma unroll
    for (int g = 0; g < 4; ++g) {
        float4 bm = bm4[g], dt = dt4[g], o;
        o.x = dt.x * inv * bm.x; o.y = dt.y * inv * bm.y;
        o.z = dt.z * inv * bm.z; o.w = dt.w * inv * bm.w;
        abp4[g * 256 + t] = o;
    }
}

// ---------- K4: hpart[p][b,c,s] = sum_{l in chunk p} x[b,c,l]*AB[b,s,l] ----------
// v3: 256c x 64s tile, acc 8x8, split-K x16 (1024 blocks), swizzled x tile.
constexpr int KP4 = 256;
constexpr size_t HP_STRIDE = (size_t)BN * DM * SD;   // floats per partial
__global__ __launch_bounds__(256) void k4_h(const float* __restrict__ x,
                                            const float* __restrict__ conv,
                                            float* __restrict__ hpart) {
    int c0 = blockIdx.x * 256;    // 2 c-tiles
    int part = blockIdx.y;        // 16 parts
    int b = blockIdx.z;
    int kbeg = part * KP4;
    __shared__ float xlf[16][264];   // [l][c], swizzled f4 blocks
    __shared__ float al[16][68];     // [l][s]
    int t = threadIdx.x;
    int tc = t & 31, ts = t >> 5;    // tc: c-group (8 c), ts: s-group (8 s)
    float acc[8][8] = {};
    const float* xb = x + (size_t)b * DM * LL;
    const float* abb = conv + (size_t)b * C3 * LL;   // AB channels 0..63

    // x staging: row cr (+64j), f4 along l at lj
    int cr = t >> 2, lj = t & 3;
    int ep[4];
#pragma unroll
    for (int j = 0; j < 4; ++j) {
        int c = cr + 64 * j;
        int cb = c >> 2, pb = cb >> 1;
        ep[j] = ((((pb ^ ((pb >> 2) & 3)) << 1) | (cb & 1)) << 2) + (c & 3);
    }
    int rp = (tc ^ ((tc >> 2) & 3)) * 2;

    float4 xv[4];
#pragma unroll
    for (int j = 0; j < 4; ++j)
        xv[j] = *(const float4*)&xb[(size_t)(c0 + cr + 64 * j) * LL + kbeg + lj * 4];
    float4 av = *(const float4*)&abb[(size_t)cr * LL + kbeg + lj * 4];

    for (int k0 = kbeg; k0 < kbeg + KP4; k0 += 16) {
#pragma unroll
        for (int j = 0; j < 4; ++j) {
            xlf[lj * 4 + 0][ep[j]] = xv[j].x;
            xlf[lj * 4 + 1][ep[j]] = xv[j].y;
            xlf[lj * 4 + 2][ep[j]] = xv[j].z;
            xlf[lj * 4 + 3][ep[j]] = xv[j].w;
        }
        al[lj * 4 + 0][cr] = av.x;
        al[lj * 4 + 1][cr] = av.y;
        al[lj * 4 + 2][cr] = av.z;
        al[lj * 4 + 3][cr] = av.w;
        __syncthreads();
        if (k0 + 16 < kbeg + KP4) {
#pragma unroll
            for (int j = 0; j < 4; ++j)
                xv[j] = *(const float4*)&xb[(size_t)(c0 + cr + 64 * j) * LL + k0 + 16 + lj * 4];
            av = *(const float4*)&abb[(size_t)cr * LL + k0 + 16 + lj * 4];
        }
#pragma unroll
        for (int kk = 0; kk < 16; ++kk) {
            float4 a0 = *(const float4*)&xlf[kk][rp * 4];
            float4 a1 = *(const float4*)&xlf[kk][rp * 4 + 4];
            float4 b0 = *(const float4*)&al[kk][ts * 8];
            float4 b1 = *(const float4*)&al[kk][ts * 8 + 4];
            OUTER64(acc, a0, a1, b0, b1)
        }
        __syncthreads();
    }
    float* hp = hpart + (size_t)part * HP_STRIDE + (size_t)b * DM * SD;
#pragma unroll
    for (int i = 0; i < 8; ++i) {
        float* row = &hp[(size_t)(c0 + tc * 8 + i) * SD + ts * 8];
        *(float4*)&row[0] = make_float4(acc[i][0], acc[i][1], acc[i][2], acc[i][3]);
        *(float4*)&row[4] = make_float4(acc[i][4], acc[i][5], acc[i][6], acc[i][7]);
    }
}

// ---------- K4r: h = sum over 16 partials ----------
__global__ __launch_bounds__(256) void k4r(const float* __restrict__ hpart,
                                           float* __restrict__ h) {
    size_t i = (size_t)blockIdx.x * 256 + threadIdx.x;   // float4 index
    const float4* hp = (const float4*)hpart;
    constexpr size_t PS = HP_STRIDE / 4;                 // 262144 float4s
    float4 a = hp[i];
#pragma unroll
    for (int p = 1; p < 16; ++p) {
        float4 v = hp[i + (size_t)p * PS];
        a.x += v.x; a.y += v.y; a.z += v.z; a.w += v.w;
    }
    ((float4*)h)[i] = a;
}

// ---------- K5: plain hz GEMM: hz[b,o,s] = sum_c w_hz[o,c]*h[b,c,s] + b_hz[o], M=1024 ----------
__global__ __launch_bounds__(256) void k5_hz(const float* __restrict__ w,
                                             const float* __restrict__ bias,
                                             const float* __restrict__ h,
                                             float* __restrict__ hz) {
    int b = blockIdx.y, o0 = blockIdx.x * 64;   // 16 o-tiles over 1024 rows
    __shared__ float wl[16][64];
    __shared__ float hl[16][64];
    int t = threadIdx.x, tx = t & 15, ty = t >> 4;
    float acc[4][4] = {};
    const float* hb = h + (size_t)b * DM * SD;
    int oi = t >> 2, kkw = (t & 3) * 4;
    int kh = t >> 4, sh = (t & 15) * 4;
    for (int k0 = 0; k0 < DM; k0 += 16) {
        float4 wv = *(const float4*)&w[(size_t)(o0 + oi) * DM + k0 + kkw];
        wl[kkw + 0][oi] = wv.x; wl[kkw + 1][oi] = wv.y;
        wl[kkw + 2][oi] = wv.z; wl[kkw + 3][oi] = wv.w;
        *(float4*)&hl[kh][sh] = *(const float4*)&hb[(size_t)(k0 + kh) * SD + sh];
        __syncthreads();
#pragma unroll
        for (int kk = 0; kk < 16; ++kk) {
            float4 a4 = *(const float4*)&wl[kk][ty * 4];
            float4 b4 = *(const float4*)&hl[kk][tx * 4];
            OUTER16(acc, a4, b4)
        }
        __syncthreads();
    }
#pragma unroll
    for (int r = 0; r < 4; ++r) {
        int o = o0 + ty * 4 + r;
        float bo = bias[o];
        *(float4*)&hz[((size_t)b * 1024 + o) * SD + tx * 4] =
            make_float4(acc[r][0] + bo, acc[r][1] + bo, acc[r][2] + bo, acc[r][3] + bo);
    }
}

// ---------- K5c: ho = w_out * gate(hz) + b_out, silu-gate fused into LDS staging ----------
__global__ __launch_bounds__(256) void k5c_gate(const float* __restrict__ w,
                                                const float* __restrict__ bias,
                                                const float* __restrict__ hz,
                                                const float* __restrict__ dskip,
                                                float* __restrict__ ho_out) {
    int b = blockIdx.y, o0 = blockIdx.x * 64;
    __shared__ float wl[16][64];
    __shared__ float hl[16][64];
    int t = threadIdx.x, tx = t & 15, ty = t >> 4;
    float acc[4][4] = {};
    const float* hzb = hz + (size_t)b * 1024 * SD;
    float d = dskip[0];
    int oi = t >> 2, kkw = (t & 3) * 4;
    int kh = t >> 4, sh = (t & 15) * 4;
    for (int k0 = 0; k0 < DM; k0 += 16) {
        float4 wv = *(const float4*)&w[(size_t)(o0 + oi) * DM + k0 + kkw];
        wl[kkw + 0][oi] = wv.x; wl[kkw + 1][oi] = wv.y;
        wl[kkw + 2][oi] = wv.z; wl[kkw + 3][oi] = wv.w;
        float4 h1 = *(const float4*)&hzb[(size_t)(k0 + kh) * SD + sh];
        float4 zz = *(const float4*)&hzb[(size_t)(512 + k0 + kh) * SD + sh];
        float4 g;
        g.x = h1.x * (zz.x / (1.f + expf(-zz.x)) + d);
        g.y = h1.y * (zz.y / (1.f + expf(-zz.y)) + d);
        g.z = h1.z * (zz.z / (1.f + expf(-zz.z)) + d);
        g.w = h1.w * (zz.w / (1.f + expf(-zz.w)) + d);
        *(float4*)&hl[kh][sh] = g;
        __syncthreads();
#pragma unroll
        for (int kk = 0; kk < 16; ++kk) {
            float4 a4 = *(const float4*)&wl[kk][ty * 4];
            float4 b4 = *(const float4*)&hl[kk][tx * 4];
            OUTER16(acc, a4, b4)
        }
        __syncthreads();
    }
#pragma unroll
    for (int r = 0; r < 4; ++r) {
        int o = o0 + ty * 4 + r;
        float bo = bias[o];
        *(float4*)&ho_out[((size_t)b * DM + o) * SD + tx * 4] =
            make_float4(acc[r][0] + bo, acc[r][1] + bo, acc[r][2] + bo, acc[r][3] + bo);
    }
}

// ---------- K6: y[b,c,l] = sum_s ho[b,c,s]*Cm[b,s,l] ----------
// v3: 128c x 128l tile, acc 8x8, swizzled cl tile.
__global__ __launch_bounds__(256) void k6_y(const float* __restrict__ ho,
                                            const float* __restrict__ cmws,
                                            float* __restrict__ y) {
    int c0 = blockIdx.x * 128;   // 4 c-tiles
    int l0 = blockIdx.y * 128;   // 32 l-tiles
    int b = blockIdx.z;
    __shared__ float hl[16][132];    // [k][c]
    __shared__ float clf[16][136];   // [k][l], swizzled f4 blocks (34 f4)
    int t = threadIdx.x;
    int tcol = t & 15, trow = t >> 4;   // tcol: l-group (8 l), trow: c-group (8 c)
    float acc[8][8] = {};
    const float* hb = ho + (size_t)b * DM * SD;
    const float* cm = cmws + (size_t)b * SD * LL;
    int cr = t & 127, kj = t >> 7;     // hl staging
    int krr = t >> 4, ch = t & 15;     // cl staging
    int wp0 = (ch ^ ((ch >> 2) & 3)) * 2;
    int rp = (tcol ^ ((tcol >> 2) & 3)) * 2;

    float4 hv0 = *(const float4*)&hb[(size_t)(c0 + cr) * SD + kj * 8];
    float4 hv1 = *(const float4*)&hb[(size_t)(c0 + cr) * SD + kj * 8 + 4];
    float4 cv0 = *(const float4*)&cm[(size_t)krr * LL + l0 + ch * 8];
    float4 cv1 = *(const float4*)&cm[(size_t)krr * LL + l0 + ch * 8 + 4];

    for (int k0 = 0; k0 < SD; k0 += 16) {
        hl[kj * 8 + 0][cr] = hv0.x; hl[kj * 8 + 1][cr] = hv0.y;
        hl[kj * 8 + 2][cr] = hv0.z; hl[kj * 8 + 3][cr] = hv0.w;
        hl[kj * 8 + 4][cr] = hv1.x; hl[kj * 8 + 5][cr] = hv1.y;
        hl[kj * 8 + 6][cr] = hv1.z; hl[kj * 8 + 7][cr] = hv1.w;
        *(float4*)&clf[krr][wp0 * 4] = cv0;
        *(float4*)&clf[krr][wp0 * 4 + 4] = cv1;
        __syncthreads();
        if (k0 + 16 < SD) {
            hv0 = *(const float4*)&hb[(size_t)(c0 + cr) * SD + k0 + 16 + kj * 8];
            hv1 = *(const float4*)&hb[(size_t)(c0 + cr) * SD + k0 + 16 + kj * 8 + 4];
            cv0 = *(const float4*)&cm[(size_t)(k0 + 16 + krr) * LL + l0 + ch * 8];
            cv1 = *(const float4*)&cm[(size_t)(k0 + 16 + krr) * LL + l0 + ch * 8 + 4];
        }
#pragma unroll
        for (int kk = 0; kk < 16; ++kk) {
            float4 a0 = *(const float4*)&hl[kk][trow * 8];
            float4 a1 = *(const float4*)&hl[kk][trow * 8 + 4];
            float4 b0 = *(const float4*)&clf[kk][rp * 4];
            float4 b1 = *(const float4*)&clf[kk][rp * 4 + 4];
            OUTER64(acc, a0, a1, b0, b1)
        }
        __syncthreads();
    }
#pragma unroll
    for (int i = 0; i < 8; ++i) {
        float* row = &y[((size_t)b * DM + c0 + trow * 8 + i) * LL + l0 + tcol * 8];
        *(float4*)&row[0] = make_float4(acc[i][0], acc[i][1], acc[i][2], acc[i][3]);
        *(float4*)&row[4] = make_float4(acc[i][4], acc[i][5], acc[i][6], acc[i][7]);
    }
}

extern "C" void kernel_launch(void* const* d_in, const int* in_sizes, int n_in,
                              void* d_out, int out_size, void* d_ws, size_t ws_size,
                              hipStream_t stream) {
    const float* x      = (const float*)d_in[0];
    const float* w_bcdt = (const float*)d_in[1];
    const float* b_bcdt = (const float*)d_in[2];
    const float* w_dw   = (const float*)d_in[3];
    const float* b_dw   = (const float*)d_in[4];
    const float* w_hz   = (const float*)d_in[5];
    const float* b_hz   = (const float*)d_in[6];
    const float* w_out  = (const float*)d_in[7];
    const float* b_out  = (const float*)d_in[8];
    const float* A      = (const float*)d_in[9];
    const float* Dskip  = (const float*)d_in[10];

    float* y_out  = (float*)d_out;                      // [32,512,4096] f32 (268.4 MB)
    float* ho_out = y_out + (size_t)BN * DM * LL;       // [32,512,64]   f32 (4.2 MB)

    // Scratch staged inside the y region of d_out (all consumed before K6 writes y):
    //   conv  [32,192,4096] f32 = 100.7 MB at byte 0       (dead after K4)
    //   hpart [16][32,512,64]   =  67.1 MB at byte 128 MiB (dead after k4r)
    //   hz    [32,1024,64]      =   8.4 MB at byte 200 MiB (dead after k5c)
    float* conv  = y_out;
    float* hpart = y_out + (size_t)33554432;   // float offset (128 MiB bytes)
    float* hz    = y_out + (size_t)52428800;   // float offset (200 MiB bytes)

    // ws: Cm copy (33.5 MB) + h (4.2 MB)
    char* ws = (char*)d_ws;
    float* cmws = (float*)(ws + 0);            // [32,64,4096] f32
    float* h    = (float*)(ws + 33554432);     // [32,512,64]  f32

    k1_bcdt <<<dim3(3, 16, BN), 256, 0, stream>>>(x, w_bcdt, b_bcdt, conv);
    k2_fused<<<dim3(SD, BN),    256, 0, stream>>>(conv, w_dw, b_dw, A, cmws);
    k4_h    <<<dim3(2, 16, BN), 256, 0, stream>>>(x, conv, hpart);
    k4r     <<<dim3(1024),      256, 0, stream>>>(hpart, h);
    k5_hz   <<<dim3(16, BN),    256, 0, stream>>>(w_hz, b_hz, h, hz);
    k5c_gate<<<dim3(8, BN),     256, 0, stream>>>(w_out, b_out, hz, Dskip, ho_out);
    k6_y    <<<dim3(4, 32, BN), 256, 0, stream>>>(ho_out, cmws, y_out);
}